// Round 17
// baseline (70.893 us; speedup 1.0000x reference)
//
#include <hip/hip_runtime.h>
#include <hip/hip_fp16.h>
#include <math.h>

#define SEQ 250
#define ST  252      // padded t-stride: rows 16B-aligned (ST*4 = 1008 = 63*16)
#define NCLS 12

typedef __attribute__((ext_vector_type(4))) _Float16 half4v;
typedef __attribute__((ext_vector_type(4))) float    float4v;

// Butterfly add via DPP (zero DS-pipe ops).
// 0xB1=quad_perm xor1; 0x4E=quad_perm xor2; 0x141=row_half_mirror (lane^7,
// valid once quad-constant); 0x140=row_mirror (lane^15, once 8-group-constant).
template<int CTRL>
__device__ __forceinline__ float dpp_add(float v) {
    int t = __builtin_amdgcn_update_dpp(0, __float_as_int(v), CTRL, 0xF, 0xF, true);
    return v + __int_as_float(t);
}

__device__ __forceinline__ __half2 f_as_h2(float f) {
    union { float f; __half2 h; } u; u.f = f; return u.h;
}
__device__ __forceinline__ float h2_as_f(__half2 h) {
    union { __half2 h; float f; } u; u.h = h; return u.f;
}

// 512 threads, TWO batch elements per block.
// LDS: 2 x (s_bc 16128 + s_dlu 16128 + s_sz 8064) + h127 1024 = 81,664 B
//  -> 2 blocks/CU (<= 81,920 B/block).
// r4-r6: no register live ranges across the scan (spills -> 45 MB scratch).
// r11/r12: matrix pipe takes the x_proj projection (ph3).
// r13: ph1-MFMA regressed -> ph1/ph2 stay scalar.
// r15/r16: fold-4 and manual ping-pong both regressed -> r14 scan form kept.
// r17: PARALLEL SCAN SPLIT. 4a: waves 0-3 scan t<128 (exact, r14 form),
// waves 4-7 concurrently scan t>=128 with h=0, tracking Ssum=cumsum(dl) and
// writing packed {Ssum, y_partial} (fp16x2). Barrier. 4c: all waves apply
// the homogeneous correction y += sum_s C*h127*exp2(A2*Ssum) t-parallel.
// Sequential wall: 250 -> 128 steps.
__global__ __launch_bounds__(512)
void mamba_cls_kernel(
    const float* __restrict__ x,         // (B, 8, 250)
    const float* __restrict__ in_proj_w, // (32, 8)
    const float* __restrict__ conv_w,    // (16, 4)
    const float* __restrict__ conv_b,    // (16)
    const float* __restrict__ x_proj_w,  // (33, 16)
    const float* __restrict__ dt_proj_w, // (16, 1)
    const float* __restrict__ dt_proj_b, // (16)
    const float* __restrict__ A_log,     // (16, 16)
    const float* __restrict__ Dp,        // (16)
    const float* __restrict__ out_proj_w,// (8, 16)
    const float* __restrict__ fc_w,      // (12, 2000)
    const float* __restrict__ fc_b,      // (12)
    float* __restrict__ out)             // (B, 12)
{
    __shared__ __align__(16) __half2 s_bc [2][16 * ST];
    __shared__ __align__(16) __half2 s_dlu[2][16 * ST];
    __shared__ __align__(16) __half  s_sz [2][16 * ST];
    __shared__ __half s_h127[2][256];   // h at t=127, fp16, [p][d*16+s]

    const int tid  = threadIdx.x;
    const int p    = tid >> 8;
    const int tid8 = tid & 255;
    const int b0   = blockIdx.x * 2;

    // ---- Phase 0: stage x for BOTH problems coalesced (float4)
    {
        float4* s_xf4 = (float4*)s_dlu[0];
        const float4* __restrict__ xb4 =
            (const float4*)(x + (size_t)b0 * (8 * SEQ));
        for (int i = tid; i < 1000; i += 512) s_xf4[i] = xb4[i];
    }
    __syncthreads();

    // ---- Phase 1: x_in[d*ST+t] -> s_bc(f32) ; silu(z) -> s_sz   (r12 form)
    {
        float* s_f  = (float*)s_bc[p];
        const float* s_xf = (const float*)s_dlu[0] + p * (8 * SEQ);
        const int d  = tid8 & 15;
        const int t0 = tid8 >> 4;
        float w1[8], w2[8];
        #pragma unroll
        for (int m = 0; m < 8; ++m) {
            w1[m] = in_proj_w[d * 8 + m];
            w2[m] = in_proj_w[(16 + d) * 8 + m];
        }
        #pragma unroll
        for (int i = 0; i < 16; ++i) {
            int t = t0 + i * 16;
            if (t < SEQ) {
                float acc = 0.f, z = 0.f;
                #pragma unroll
                for (int m = 0; m < 8; ++m) {
                    float xv = s_xf[m * SEQ + t];
                    acc = fmaf(w1[m], xv, acc);
                    z   = fmaf(w2[m], xv, z);
                }
                s_f[d * ST + t] = acc;
                s_sz[p][d * ST + t] = __float2half(z / (1.f + __expf(-z)));
            }
        }
    }
    __syncthreads();

    // ---- Phase 2: causal conv(k=4)+SiLU -> u into s_dlu[p][d*ST+t].y (r12)
    {
        const float* s_f = (const float*)s_bc[p];
        const int d  = tid8 & 15;
        const int t0 = tid8 >> 4;
        float cw[4];
        #pragma unroll
        for (int k = 0; k < 4; ++k) cw[k] = conv_w[d * 4 + k];
        const float cb = conv_b[d];
        #pragma unroll
        for (int i = 0; i < 16; ++i) {
            int t = t0 + i * 16;
            if (t < SEQ) {
                float acc = cb;
                #pragma unroll
                for (int k = 0; k < 4; ++k) {
                    int tt = t + k - 3;
                    if (tt >= 0) acc = fmaf(cw[k], s_f[d * ST + tt], acc);
                }
                float sg = 1.f / (1.f + __expf(-acc));
                s_dlu[p][d * ST + t].y = __float2half(acc * sg);
            }
        }
    }
    __syncthreads();

    // ---- Phase 3 (MFMA): per 16-t tile, D = u(16t x 16d) * W(16d x 16col)
    // via v_mfma_f32_16x16x16f16 (fragment map verified r12).
    {
        const int wave = tid8 >> 6;       // 0..3
        const int l    = tid8 & 63;
        const int rowc = l & 15;          // A-row (t_local) AND D-col (state)
        const int kg   = l >> 4;          // k-group

        half4v wB, wC, wD;
        #pragma unroll
        for (int i = 0; i < 4; ++i) {
            wB[i] = (_Float16)x_proj_w[(1  + rowc) * 16 + 4 * kg + i];
            wC[i] = (_Float16)x_proj_w[(17 + rowc) * 16 + 4 * kg + i];
            wD[i] = (_Float16)x_proj_w[4 * kg + i];
        }
        const float dtw_c = dt_proj_w[rowc];
        const float dtb_c = dt_proj_b[rowc];
        const float4v zero4 = {0.f, 0.f, 0.f, 0.f};
        const unsigned int* __restrict__ dlu_w = (const unsigned int*)s_dlu[p];

        for (int tile = wave; tile < 16; tile += 4) {
            const int t0 = tile * 16;
            unsigned int w0 = dlu_w[(4 * kg + 0) * ST + t0 + rowc];
            unsigned int w1 = dlu_w[(4 * kg + 1) * ST + t0 + rowc];
            unsigned int w2 = dlu_w[(4 * kg + 2) * ST + t0 + rowc];
            unsigned int w3 = dlu_w[(4 * kg + 3) * ST + t0 + rowc];
            union { unsigned int u[2]; half4v h; } A;
            A.u[0] = (w0 >> 16) | (w1 & 0xFFFF0000u);
            A.u[1] = (w2 >> 16) | (w3 & 0xFFFF0000u);

            float4v dB = __builtin_amdgcn_mfma_f32_16x16x16f16(A.h, wB, zero4, 0, 0, 0);
            float4v dC = __builtin_amdgcn_mfma_f32_16x16x16f16(A.h, wC, zero4, 0, 0, 0);
            float4v dT = __builtin_amdgcn_mfma_f32_16x16x16f16(A.h, wD, zero4, 0, 0, 0);

            const int tb = t0 + kg * 4;
            if (tb <= 248) {
                __half2 h0 = __floats2half2_rn(dB[0], dC[0]);
                __half2 h1 = __floats2half2_rn(dB[1], dC[1]);
                __half2 h2 = __floats2half2_rn(dB[2], dC[2]);
                __half2 h3 = __floats2half2_rn(dB[3], dC[3]);
                float4 wv;
                wv.x = h2_as_f(h0); wv.y = h2_as_f(h1);
                wv.z = h2_as_f(h2); wv.w = h2_as_f(h3);
                *reinterpret_cast<float4*>(s_bc[p] + rowc * ST + tb) = wv;
            }
            #pragma unroll
            for (int r = 0; r < 4; ++r) {
                int t = tb + r;
                if (t < SEQ) {
                    float v  = fmaf(dT[r], dtw_c, dtb_c);
                    float dl = (v > 20.f) ? v : __logf(1.f + __expf(v));
                    s_dlu[p][rowc * ST + t].x = __float2half(dl);
                }
            }
        }
    }
    __syncthreads();

    // ---- Phase 4a: split scan, ALL 8 waves.
    // waves 0-3 (tid<256): first half t in [0,128), exact r14 form; write h127.
    // waves 4-7: second half t in [128,250), h=0 start, track Ssum=cumsum(dl),
    // write packed {Ssum, y_partial} (fp16x2) into the y slot (y_part = r + u*D,
    // WITHOUT sz; sz applied in 4c).
    {
        const int sp = (tid >> 7) & 1;
        const int i7 = tid & 127;
        const int d  = i7 >> 3;
        const int s2 = i7 & 7;
        const float A2a = -__expf(A_log[d * 16 + s2])     * 1.4426950408889634f;
        const float A2b = -__expf(A_log[d * 16 + s2 + 8]) * 1.4426950408889634f;
        const float Dd  = Dp[d];
        const __half2* __restrict__ dlu_p = s_dlu[sp] + d * ST;
        const __half2* __restrict__ bca_p = s_bc [sp] + s2 * ST;
        const __half2* __restrict__ bcb_p = s_bc [sp] + (s2 + 8) * ST;
        float* __restrict__ y_p = (float*)s_dlu[sp] + d * ST;
        float ha = 0.f, hb = 0.f;

        if (tid < 256) {
            const __half* __restrict__ sz_p = (const __half*)s_sz[sp] + d * ST;
            for (int t = 0; t < 128; t += 8) {
                float4 du_a = *reinterpret_cast<const float4*>(dlu_p + t);
                float4 du_b = *reinterpret_cast<const float4*>(dlu_p + t + 4);
                float4 ba_a = *reinterpret_cast<const float4*>(bca_p + t);
                float4 ba_b = *reinterpret_cast<const float4*>(bca_p + t + 4);
                float4 bb_a = *reinterpret_cast<const float4*>(bcb_p + t);
                float4 bb_b = *reinterpret_cast<const float4*>(bcb_p + t + 4);
                float2 sza  = *reinterpret_cast<const float2*>(sz_p + t);
                float2 szb  = *reinterpret_cast<const float2*>(sz_p + t + 4);

                float fdu[8] = {du_a.x, du_a.y, du_a.z, du_a.w,
                                du_b.x, du_b.y, du_b.z, du_b.w};
                float fba[8] = {ba_a.x, ba_a.y, ba_a.z, ba_a.w,
                                ba_b.x, ba_b.y, ba_b.z, ba_b.w};
                float fbb[8] = {bb_a.x, bb_a.y, bb_a.z, bb_a.w,
                                bb_b.x, bb_b.y, bb_b.z, bb_b.w};
                float2 s0 = __half22float2(f_as_h2(sza.x));
                float2 s1 = __half22float2(f_as_h2(sza.y));
                float2 s2f = __half22float2(f_as_h2(szb.x));
                float2 s3 = __half22float2(f_as_h2(szb.y));
                float fsz[8] = {s0.x, s0.y, s1.x, s1.y, s2f.x, s2f.y, s3.x, s3.y};

                float yv[8];
                #pragma unroll
                for (int q = 0; q < 8; ++q) {
                    float2 du  = __half22float2(f_as_h2(fdu[q]));
                    float2 bca = __half22float2(f_as_h2(fba[q]));
                    float2 bcb = __half22float2(f_as_h2(fbb[q]));
                    float dlu = du.x * du.y;
                    ha = fmaf(exp2f(du.x * A2a), ha, dlu * bca.x);
                    hb = fmaf(exp2f(du.x * A2b), hb, dlu * bcb.x);
                    float r = fmaf(hb, bcb.y, ha * bca.y);
                    r = dpp_add<0xB1>(r);
                    r = dpp_add<0x4E>(r);
                    r = dpp_add<0x141>(r);
                    yv[q] = fmaf(du.y, Dd, r) * fsz[q];
                }
                if (s2 == 0) {
                    float4 y4;
                    y4.x = yv[0]; y4.y = yv[1]; y4.z = yv[2]; y4.w = yv[3];
                    *reinterpret_cast<float4*>(y_p + t) = y4;
                    y4.x = yv[4]; y4.y = yv[5]; y4.z = yv[6]; y4.w = yv[7];
                    *reinterpret_cast<float4*>(y_p + t + 4) = y4;
                }
            }
            // handoff h at t=127 (fp16)
            s_h127[sp][d * 16 + s2]     = __float2half(ha);
            s_h127[sp][d * 16 + s2 + 8] = __float2half(hb);
        } else {
            float Ssum = 0.f;
            for (int t = 128; t < 248; t += 8) {
                float4 du_a = *reinterpret_cast<const float4*>(dlu_p + t);
                float4 du_b = *reinterpret_cast<const float4*>(dlu_p + t + 4);
                float4 ba_a = *reinterpret_cast<const float4*>(bca_p + t);
                float4 ba_b = *reinterpret_cast<const float4*>(bca_p + t + 4);
                float4 bb_a = *reinterpret_cast<const float4*>(bcb_p + t);
                float4 bb_b = *reinterpret_cast<const float4*>(bcb_p + t + 4);

                float fdu[8] = {du_a.x, du_a.y, du_a.z, du_a.w,
                                du_b.x, du_b.y, du_b.z, du_b.w};
                float fba[8] = {ba_a.x, ba_a.y, ba_a.z, ba_a.w,
                                ba_b.x, ba_b.y, ba_b.z, ba_b.w};
                float fbb[8] = {bb_a.x, bb_a.y, bb_a.z, bb_a.w,
                                bb_b.x, bb_b.y, bb_b.z, bb_b.w};
                float wpk[8];
                #pragma unroll
                for (int q = 0; q < 8; ++q) {
                    float2 du  = __half22float2(f_as_h2(fdu[q]));
                    float2 bca = __half22float2(f_as_h2(fba[q]));
                    float2 bcb = __half22float2(f_as_h2(fbb[q]));
                    Ssum += du.x;
                    float dlu = du.x * du.y;
                    ha = fmaf(exp2f(du.x * A2a), ha, dlu * bca.x);
                    hb = fmaf(exp2f(du.x * A2b), hb, dlu * bcb.x);
                    float r = fmaf(hb, bcb.y, ha * bca.y);
                    r = dpp_add<0xB1>(r);
                    r = dpp_add<0x4E>(r);
                    r = dpp_add<0x141>(r);
                    float ypart = fmaf(du.y, Dd, r);
                    wpk[q] = h2_as_f(__floats2half2_rn(Ssum, ypart));
                }
                if (s2 == 0) {
                    float4 y4;
                    y4.x = wpk[0]; y4.y = wpk[1]; y4.z = wpk[2]; y4.w = wpk[3];
                    *reinterpret_cast<float4*>(y_p + t) = y4;
                    y4.x = wpk[4]; y4.y = wpk[5]; y4.z = wpk[6]; y4.w = wpk[7];
                    *reinterpret_cast<float4*>(y_p + t + 4) = y4;
                }
            }
            {   // tail t = 248, 249
                float2 duv2 = *reinterpret_cast<const float2*>(dlu_p + 248);
                float2 bca2 = *reinterpret_cast<const float2*>(bca_p + 248);
                float2 bcb2 = *reinterpret_cast<const float2*>(bcb_p + 248);
                float fdu[2] = {duv2.x, duv2.y};
                float fba[2] = {bca2.x, bca2.y};
                float fbb[2] = {bcb2.x, bcb2.y};
                float wpk[2];
                #pragma unroll
                for (int q = 0; q < 2; ++q) {
                    float2 du  = __half22float2(f_as_h2(fdu[q]));
                    float2 bca = __half22float2(f_as_h2(fba[q]));
                    float2 bcb = __half22float2(f_as_h2(fbb[q]));
                    Ssum += du.x;
                    float dlu = du.x * du.y;
                    ha = fmaf(exp2f(du.x * A2a), ha, dlu * bca.x);
                    hb = fmaf(exp2f(du.x * A2b), hb, dlu * bcb.x);
                    float r = fmaf(hb, bcb.y, ha * bca.y);
                    r = dpp_add<0xB1>(r);
                    r = dpp_add<0x4E>(r);
                    r = dpp_add<0x141>(r);
                    float ypart = fmaf(du.y, Dd, r);
                    wpk[q] = h2_as_f(__floats2half2_rn(Ssum, ypart));
                }
                if (s2 == 0) {
                    float2 y2; y2.x = wpk[0]; y2.y = wpk[1];
                    *reinterpret_cast<float2*>(y_p + 248) = y2;
                }
            }
        }
    }
    __syncthreads();

    // ---- Phase 4c: correction for t in [128,250), ALL 8 waves, t-parallel.
    // thread = (d = tid8>>4, s = tid8&15); per t: corr = C_t[s]*h127[d,s]*
    // exp2(A2[d,s]*Ssum_t); 4-stage DPP sum over s; y = (ypart + corr)*sz.
    {
        const int d = tid8 >> 4;
        const int s = tid8 & 15;
        const float A2 = -__expf(A_log[d * 16 + s]) * 1.4426950408889634f;
        const float hmid = __half2float(s_h127[p][d * 16 + s]);
        float* __restrict__ y_row = (float*)s_dlu[p] + d * ST;
        const __half2* __restrict__ bc_row = s_bc[p] + s * ST;
        const __half*  __restrict__ sz_row = (const __half*)s_sz[p] + d * ST;
        for (int t = 128; t < 250; t += 2) {
            float2 w2 = *reinterpret_cast<const float2*>(y_row + t);   // {Ssum,ypart} x2
            float2 c2 = *reinterpret_cast<const float2*>(bc_row + t);  // {B,C} x2
            float  szw = *reinterpret_cast<const float*>(sz_row + t);  // sz x2
            float2 szv = __half22float2(f_as_h2(szw));

            float2 w0 = __half22float2(f_as_h2(w2.x));
            float2 w1 = __half22float2(f_as_h2(w2.y));
            float  C0 = __half22float2(f_as_h2(c2.x)).y;
            float  C1 = __half22float2(f_as_h2(c2.y)).y;

            float corr0 = C0 * hmid * exp2f(A2 * w0.x);
            corr0 = dpp_add<0xB1>(corr0);
            corr0 = dpp_add<0x4E>(corr0);
            corr0 = dpp_add<0x141>(corr0);
            corr0 = dpp_add<0x140>(corr0);
            float corr1 = C1 * hmid * exp2f(A2 * w1.x);
            corr1 = dpp_add<0xB1>(corr1);
            corr1 = dpp_add<0x4E>(corr1);
            corr1 = dpp_add<0x141>(corr1);
            corr1 = dpp_add<0x140>(corr1);
            if (s == 0) {
                y_row[t]     = (w0.y + corr0) * szv.x;
                y_row[t + 1] = (w1.y + corr1) * szv.y;
            }
        }
    }
    __syncthreads();

    // ---- Phase 5b: out2000[t*8+j] = sum_d y[d,t]*out_proj_w[j,d]
    {
        float* s_f  = (float*)s_bc[p];
        const float* s_yf = (const float*)s_dlu[p];
        const int j = tid8 & 7;
        float w[16];
        #pragma unroll
        for (int d2 = 0; d2 < 16; ++d2) w[d2] = out_proj_w[j * 16 + d2];
        for (int t0 = (tid8 >> 3) * 4; t0 < SEQ; t0 += 128) {
            float a0 = 0.f, a1 = 0.f, a2 = 0.f, a3 = 0.f;
            #pragma unroll
            for (int d2 = 0; d2 < 16; ++d2) {
                float4 y4 = *reinterpret_cast<const float4*>(s_yf + d2 * ST + t0);
                a0 = fmaf(w[d2], y4.x, a0);
                a1 = fmaf(w[d2], y4.y, a1);
                a2 = fmaf(w[d2], y4.z, a2);
                a3 = fmaf(w[d2], y4.w, a3);
            }
            s_f[(t0 + 0) * 8 + j] = a0;
            s_f[(t0 + 1) * 8 + j] = a1;
            if (t0 + 2 < SEQ) s_f[(t0 + 2) * 8 + j] = a2;
            if (t0 + 3 < SEQ) s_f[(t0 + 3) * 8 + j] = a3;
        }
    }
    __syncthreads();

    // ---- Phase 6: logits[c] = out2000 . fc_w[c,:] + fc_b[c]  (float4 loads)
    {
        float* s_yf = (float*)s_dlu[p];
        float p_[NCLS];
        #pragma unroll
        for (int c = 0; c < NCLS; ++c) p_[c] = 0.f;
        const float4* fw4 = (const float4*)fc_w;
        const float4* sf4 = (const float4*)s_bc[p];
        for (int q = tid8; q < 500; q += 256) {
            float4 f = sf4[q];
            #pragma unroll
            for (int c = 0; c < NCLS; ++c) {
                float4 wv = fw4[c * 500 + q];
                p_[c] += f.x * wv.x + f.y * wv.y + f.z * wv.z + f.w * wv.w;
            }
        }
        #pragma unroll
        for (int c = 0; c < NCLS; ++c) {
            float v = p_[c];
            v = dpp_add<0xB1>(v);
            v = dpp_add<0x4E>(v);
            v = dpp_add<0x141>(v);
            v = dpp_add<0x140>(v);
            v += __shfl_xor(v, 16);
            v += __shfl_xor(v, 32);
            p_[c] = v;
        }
        const int wave = tid8 >> 6;
        const int lane = tid8 & 63;
        __syncthreads();
        if (lane == 0) {
            #pragma unroll
            for (int c = 0; c < NCLS; ++c) s_yf[wave * NCLS + c] = p_[c];
        }
        __syncthreads();
        if (tid8 < NCLS) {
            float v = s_yf[tid8] + s_yf[NCLS + tid8] + s_yf[2 * NCLS + tid8] +
                      s_yf[3 * NCLS + tid8] + fc_b[tid8];
            out[(size_t)(b0 + p) * NCLS + tid8] = v;
        }
    }
}

extern "C" void kernel_launch(void* const* d_in, const int* in_sizes, int n_in,
                              void* d_out, int out_size, void* d_ws, size_t ws_size,
                              hipStream_t stream) {
    const float* x          = (const float*)d_in[0];
    const float* in_proj_w  = (const float*)d_in[1];
    const float* conv_w     = (const float*)d_in[2];
    const float* conv_b     = (const float*)d_in[3];
    const float* x_proj_w   = (const float*)d_in[4];
    const float* dt_proj_w  = (const float*)d_in[5];
    const float* dt_proj_b  = (const float*)d_in[6];
    const float* A_log      = (const float*)d_in[7];
    const float* Dp         = (const float*)d_in[8];
    const float* out_proj_w = (const float*)d_in[9];
    const float* fc_w       = (const float*)d_in[10];
    const float* fc_b       = (const float*)d_in[11];
    float* out = (float*)d_out;

    const int batch = in_sizes[0] / (8 * SEQ);  // 1024
    mamba_cls_kernel<<<batch / 2, 512, 0, stream>>>(
        x, in_proj_w, conv_w, conv_b, x_proj_w, dt_proj_w, dt_proj_b,
        A_log, Dp, out_proj_w, fc_w, fc_b, out);
}

// Round 18
// 68.388 us; speedup vs baseline: 1.0366x; 1.0366x over previous
//
#include <hip/hip_runtime.h>
#include <hip/hip_fp16.h>
#include <math.h>

#define SEQ 250
#define ST  252      // padded t-stride: rows 16B-aligned (ST*4 = 1008 = 63*16)
#define NCLS 12

typedef __attribute__((ext_vector_type(4))) _Float16 half4v;
typedef __attribute__((ext_vector_type(4))) float    float4v;

// Butterfly add via DPP (zero DS-pipe ops).
// 0xB1=quad_perm xor1; 0x4E=quad_perm xor2; 0x141=row_half_mirror (lane^7,
// valid once quad-constant); 0x140=row_mirror (lane^15, once 8-group-constant).
template<int CTRL>
__device__ __forceinline__ float dpp_add(float v) {
    int t = __builtin_amdgcn_update_dpp(0, __float_as_int(v), CTRL, 0xF, 0xF, true);
    return v + __int_as_float(t);
}

__device__ __forceinline__ __half2 f_as_h2(float f) {
    union { float f; __half2 h; } u; u.f = f; return u.h;
}
__device__ __forceinline__ float h2_as_f(__half2 h) {
    union { __half2 h; float f; } u; u.h = h; return u.f;
}

// 512 threads, TWO batch elements per block.
// LDS: 2 x (s_bc 16128 + s_dlu 16128 + s_sz 8064) = 80,640 B -> 2 blocks/CU.
// r4-r6: no register live ranges across the scan (spills -> 45 MB scratch).
// r11/r12: matrix pipe takes the x_proj projection (ph3).
// r13: ph1-MFMA regressed -> projections via MFMA only where gather is cheap.
// r15/r16/r17: fold-4, manual ping-pong, and parallel-split scans ALL
// regressed -> r14 scan form is the local optimum; scan untouched.
// r18: phases 1+2 FUSED on (d, contiguous 16-t chunk) mapping: x read as
// b128, x_in lives in registers (conv boundary recomputed), u written as
// b128 {0,u} words, sz as b128; one barrier removed. x stages into s_bc
// (free until ph3 writes {B,C}).
__global__ __launch_bounds__(512)
void mamba_cls_kernel(
    const float* __restrict__ x,         // (B, 8, 250)
    const float* __restrict__ in_proj_w, // (32, 8)
    const float* __restrict__ conv_w,    // (16, 4)
    const float* __restrict__ conv_b,    // (16)
    const float* __restrict__ x_proj_w,  // (33, 16)
    const float* __restrict__ dt_proj_w, // (16, 1)
    const float* __restrict__ dt_proj_b, // (16)
    const float* __restrict__ A_log,     // (16, 16)
    const float* __restrict__ Dp,        // (16)
    const float* __restrict__ out_proj_w,// (8, 16)
    const float* __restrict__ fc_w,      // (12, 2000)
    const float* __restrict__ fc_b,      // (12)
    float* __restrict__ out)             // (B, 12)
{
    __shared__ __align__(16) __half2 s_bc [2][16 * ST];
    __shared__ __align__(16) __half2 s_dlu[2][16 * ST];
    __shared__ __align__(16) __half  s_sz [2][16 * ST];

    const int tid  = threadIdx.x;
    const int p    = tid >> 8;
    const int tid8 = tid & 255;
    const int b0   = blockIdx.x * 2;

    // ---- Phase 0: stage x for BOTH problems coalesced (float4) into s_bc
    {
        float4* s_xf4 = (float4*)s_bc[0];
        const float4* __restrict__ xb4 =
            (const float4*)(x + (size_t)b0 * (8 * SEQ));
        for (int i = tid; i < 1000; i += 512) s_xf4[i] = xb4[i];
    }
    __syncthreads();

    // ---- Phase 1+2 FUSED: per (d, 16-t chunk): x via b128, x_in in regs,
    // conv+SiLU -> u as b128 {0,u} words; silu(z) -> s_sz as b128.
    {
        const float* s_xf = (const float*)s_bc[0] + p * (8 * SEQ);
        const int d  = tid8 & 15;
        const int c  = tid8 >> 4;     // chunk 0..15
        const int t0 = c * 16;
        float w1[8], w2[8], cw[4];
        #pragma unroll
        for (int m = 0; m < 8; ++m) {
            w1[m] = in_proj_w[d * 8 + m];
            w2[m] = in_proj_w[(16 + d) * 8 + m];
        }
        #pragma unroll
        for (int k = 0; k < 4; ++k) cw[k] = conv_w[d * 4 + k];
        const float cb = conv_b[d];

        // left boundary x_in at t0-3..t0-1 (recomputed; zero at t0==0)
        float xm3 = 0.f, xm2 = 0.f, xm1 = 0.f;
        if (t0 > 0) {
            #pragma unroll
            for (int m = 0; m < 8; ++m) {
                float a = s_xf[m * SEQ + t0 - 3];
                float b = s_xf[m * SEQ + t0 - 2];
                float cc = s_xf[m * SEQ + t0 - 1];
                xm3 = fmaf(w1[m], a, xm3);
                xm2 = fmaf(w1[m], b, xm2);
                xm1 = fmaf(w1[m], cc, xm1);
            }
        }

        float xin[16];
        __half szh[16];
        #pragma unroll
        for (int g = 0; g < 4; ++g) {           // 4 t's per group
            float4 xv[8];
            #pragma unroll
            for (int m = 0; m < 8; ++m)
                xv[m] = *reinterpret_cast<const float4*>(s_xf + m * SEQ + t0 + g * 4);
            #pragma unroll
            for (int j = 0; j < 4; ++j) {
                float acc = 0.f, z = 0.f;
                #pragma unroll
                for (int m = 0; m < 8; ++m) {
                    float xvj = ((const float*)&xv[m])[j];
                    acc = fmaf(w1[m], xvj, acc);
                    z   = fmaf(w2[m], xvj, z);
                }
                xin[g * 4 + j] = acc;
                szh[g * 4 + j] = __float2half(z / (1.f + __expf(-z)));
            }
        }

        // sz writes (vector; tail chunk split to stay in-row)
        {
            __half* szp = (__half*)s_sz[p] + d * ST + t0;
            if (c < 15) {
                *reinterpret_cast<float4*>(szp)     = *reinterpret_cast<float4*>(&szh[0]);
                *reinterpret_cast<float4*>(szp + 8) = *reinterpret_cast<float4*>(&szh[8]);
            } else {
                *reinterpret_cast<float4*>(szp)     = *reinterpret_cast<float4*>(&szh[0]);
                *reinterpret_cast<float*>(szp + 8)  = *reinterpret_cast<float*>(&szh[8]); // t=248,249
            }
        }

        // conv(k=4)+SiLU from registers -> u packed as {0,u} words
        float uw[16];
        #pragma unroll
        for (int i = 0; i < 16; ++i) {
            float a = (i >= 3) ? xin[i - 3] : (i == 0 ? xm3 : (i == 1 ? xm2 : xm1));
            float b = (i >= 2) ? xin[i - 2] : (i == 0 ? xm2 : xm1);
            float cc = (i >= 1) ? xin[i - 1] : xm1;
            float acc = cb;
            acc = fmaf(cw[0], a,  acc);
            acc = fmaf(cw[1], b,  acc);
            acc = fmaf(cw[2], cc, acc);
            acc = fmaf(cw[3], xin[i], acc);
            float sg = 1.f / (1.f + __expf(-acc));
            uw[i] = __uint_as_float(((unsigned)__half_as_ushort(__float2half(acc * sg))) << 16);
        }
        {
            float* dlup = (float*)(s_dlu[p] + d * ST + t0);
            if (c < 15) {
                #pragma unroll
                for (int g = 0; g < 4; ++g)
                    *reinterpret_cast<float4*>(dlup + g * 4) =
                        *reinterpret_cast<float4*>(&uw[g * 4]);
            } else {
                *reinterpret_cast<float4*>(dlup)     = *reinterpret_cast<float4*>(&uw[0]);
                *reinterpret_cast<float4*>(dlup + 4) = *reinterpret_cast<float4*>(&uw[4]);
                *reinterpret_cast<float2*>(dlup + 8) = *reinterpret_cast<float2*>(&uw[8]); // t=248,249
            }
        }
    }
    __syncthreads();

    // ---- Phase 3 (MFMA): per 16-t tile, D = u(16t x 16d) * W(16d x 16col)
    // via v_mfma_f32_16x16x16f16 (fragment map verified r12).
    {
        const int wave = tid8 >> 6;       // 0..3
        const int l    = tid8 & 63;
        const int rowc = l & 15;          // A-row (t_local) AND D-col (state)
        const int kg   = l >> 4;          // k-group

        half4v wB, wC, wD;
        #pragma unroll
        for (int i = 0; i < 4; ++i) {
            wB[i] = (_Float16)x_proj_w[(1  + rowc) * 16 + 4 * kg + i];
            wC[i] = (_Float16)x_proj_w[(17 + rowc) * 16 + 4 * kg + i];
            wD[i] = (_Float16)x_proj_w[4 * kg + i];
        }
        const float dtw_c = dt_proj_w[rowc];
        const float dtb_c = dt_proj_b[rowc];
        const float4v zero4 = {0.f, 0.f, 0.f, 0.f};
        const unsigned int* __restrict__ dlu_w = (const unsigned int*)s_dlu[p];

        for (int tile = wave; tile < 16; tile += 4) {
            const int t0 = tile * 16;
            unsigned int w0 = dlu_w[(4 * kg + 0) * ST + t0 + rowc];
            unsigned int w1 = dlu_w[(4 * kg + 1) * ST + t0 + rowc];
            unsigned int w2 = dlu_w[(4 * kg + 2) * ST + t0 + rowc];
            unsigned int w3 = dlu_w[(4 * kg + 3) * ST + t0 + rowc];
            union { unsigned int u[2]; half4v h; } A;
            A.u[0] = (w0 >> 16) | (w1 & 0xFFFF0000u);
            A.u[1] = (w2 >> 16) | (w3 & 0xFFFF0000u);

            float4v dB = __builtin_amdgcn_mfma_f32_16x16x16f16(A.h, wB, zero4, 0, 0, 0);
            float4v dC = __builtin_amdgcn_mfma_f32_16x16x16f16(A.h, wC, zero4, 0, 0, 0);
            float4v dT = __builtin_amdgcn_mfma_f32_16x16x16f16(A.h, wD, zero4, 0, 0, 0);

            const int tb = t0 + kg * 4;   // first of this lane's 4 t's
            if (tb <= 248) {              // words tb..tb+3 <= 251 (pad ok)
                __half2 h0 = __floats2half2_rn(dB[0], dC[0]);
                __half2 h1 = __floats2half2_rn(dB[1], dC[1]);
                __half2 h2 = __floats2half2_rn(dB[2], dC[2]);
                __half2 h3 = __floats2half2_rn(dB[3], dC[3]);
                float4 wv;
                wv.x = h2_as_f(h0); wv.y = h2_as_f(h1);
                wv.z = h2_as_f(h2); wv.w = h2_as_f(h3);
                *reinterpret_cast<float4*>(s_bc[p] + rowc * ST + tb) = wv;
            }
            #pragma unroll
            for (int r = 0; r < 4; ++r) {
                int t = tb + r;
                if (t < SEQ) {
                    float v  = fmaf(dT[r], dtw_c, dtb_c);
                    float dl = (v > 20.f) ? v : __logf(1.f + __expf(v));
                    s_dlu[p][rowc * ST + t].x = __float2half(dl);
                }
            }
        }
    }
    __syncthreads();

    // ---- Phase 4: scan, s-folded x2, 8t batches (r14 form — proven optimum).
    // Active: tid<256. waves 0-1 -> problem 0, waves 2-3 -> problem 1.
    if (tid < 256) {
        const int sp   = tid >> 7;
        const int i7   = tid & 127;
        const int d    = i7 >> 3;
        const int s2   = i7 & 7;
        const float A2a = -__expf(A_log[d * 16 + s2])     * 1.4426950408889634f;
        const float A2b = -__expf(A_log[d * 16 + s2 + 8]) * 1.4426950408889634f;
        const float Dd  = Dp[d];
        const __half2* __restrict__ dlu_p = s_dlu[sp] + d * ST;
        const __half2* __restrict__ bca_p = s_bc [sp] + s2 * ST;
        const __half2* __restrict__ bcb_p = s_bc [sp] + (s2 + 8) * ST;
        const __half*  __restrict__ sz_p  = (const __half*)s_sz[sp] + d * ST;
        float* __restrict__ y_p = (float*)s_dlu[sp] + d * ST;
        float ha = 0.f, hb = 0.f;
        for (int t = 0; t < 248; t += 8) {
            float4 du_a = *reinterpret_cast<const float4*>(dlu_p + t);
            float4 du_b = *reinterpret_cast<const float4*>(dlu_p + t + 4);
            float4 ba_a = *reinterpret_cast<const float4*>(bca_p + t);
            float4 ba_b = *reinterpret_cast<const float4*>(bca_p + t + 4);
            float4 bb_a = *reinterpret_cast<const float4*>(bcb_p + t);
            float4 bb_b = *reinterpret_cast<const float4*>(bcb_p + t + 4);
            float2 sza  = *reinterpret_cast<const float2*>(sz_p + t);
            float2 szb  = *reinterpret_cast<const float2*>(sz_p + t + 4);

            float fdu[8] = {du_a.x, du_a.y, du_a.z, du_a.w,
                            du_b.x, du_b.y, du_b.z, du_b.w};
            float fba[8] = {ba_a.x, ba_a.y, ba_a.z, ba_a.w,
                            ba_b.x, ba_b.y, ba_b.z, ba_b.w};
            float fbb[8] = {bb_a.x, bb_a.y, bb_a.z, bb_a.w,
                            bb_b.x, bb_b.y, bb_b.z, bb_b.w};
            float2 s0 = __half22float2(f_as_h2(sza.x));
            float2 s1 = __half22float2(f_as_h2(sza.y));
            float2 s2f = __half22float2(f_as_h2(szb.x));
            float2 s3 = __half22float2(f_as_h2(szb.y));
            float fsz[8] = {s0.x, s0.y, s1.x, s1.y, s2f.x, s2f.y, s3.x, s3.y};

            float yv[8];
            #pragma unroll
            for (int tt = 0; tt < 8; ++tt) {
                float2 du  = __half22float2(f_as_h2(fdu[tt]));
                float2 bca = __half22float2(f_as_h2(fba[tt]));
                float2 bcb = __half22float2(f_as_h2(fbb[tt]));
                float dlu = du.x * du.y;
                ha = fmaf(exp2f(du.x * A2a), ha, dlu * bca.x);
                hb = fmaf(exp2f(du.x * A2b), hb, dlu * bcb.x);
                float r = fmaf(hb, bcb.y, ha * bca.y);
                r = dpp_add<0xB1>(r);
                r = dpp_add<0x4E>(r);
                r = dpp_add<0x141>(r);
                yv[tt] = fmaf(du.y, Dd, r) * fsz[tt];
            }
            if (s2 == 0) {
                float4 y4;
                y4.x = yv[0]; y4.y = yv[1]; y4.z = yv[2]; y4.w = yv[3];
                *reinterpret_cast<float4*>(y_p + t) = y4;
                y4.x = yv[4]; y4.y = yv[5]; y4.z = yv[6]; y4.w = yv[7];
                *reinterpret_cast<float4*>(y_p + t + 4) = y4;
            }
        }
        {   // tail t = 248, 249
            float2 duv2 = *reinterpret_cast<const float2*>(dlu_p + 248);
            float2 bca2 = *reinterpret_cast<const float2*>(bca_p + 248);
            float2 bcb2 = *reinterpret_cast<const float2*>(bcb_p + 248);
            float2 szf  = __half22float2(*reinterpret_cast<const __half2*>(sz_p + 248));
            float fdu[2] = {duv2.x, duv2.y};
            float fba[2] = {bca2.x, bca2.y};
            float fbb[2] = {bcb2.x, bcb2.y};
            float fsz[2] = {szf.x, szf.y};
            float yv[2];
            #pragma unroll
            for (int tt = 0; tt < 2; ++tt) {
                float2 du  = __half22float2(f_as_h2(fdu[tt]));
                float2 bca = __half22float2(f_as_h2(fba[tt]));
                float2 bcb = __half22float2(f_as_h2(fbb[tt]));
                float dlu = du.x * du.y;
                ha = fmaf(exp2f(du.x * A2a), ha, dlu * bca.x);
                hb = fmaf(exp2f(du.x * A2b), hb, dlu * bcb.x);
                float r = fmaf(hb, bcb.y, ha * bca.y);
                r = dpp_add<0xB1>(r);
                r = dpp_add<0x4E>(r);
                r = dpp_add<0x141>(r);
                yv[tt] = fmaf(du.y, Dd, r) * fsz[tt];
            }
            if (s2 == 0) {
                float2 y2; y2.x = yv[0]; y2.y = yv[1];
                *reinterpret_cast<float2*>(y_p + 248) = y2;
            }
        }
    }
    __syncthreads();

    // ---- Phase 5b: out2000[t*8+j] = sum_d y[d,t]*out_proj_w[j,d]
    {
        float* s_f  = (float*)s_bc[p];
        const float* s_yf = (const float*)s_dlu[p];
        const int j = tid8 & 7;
        float w[16];
        #pragma unroll
        for (int d2 = 0; d2 < 16; ++d2) w[d2] = out_proj_w[j * 16 + d2];
        for (int t0 = (tid8 >> 3) * 4; t0 < SEQ; t0 += 128) {
            float a0 = 0.f, a1 = 0.f, a2 = 0.f, a3 = 0.f;
            #pragma unroll
            for (int d2 = 0; d2 < 16; ++d2) {
                float4 y4 = *reinterpret_cast<const float4*>(s_yf + d2 * ST + t0);
                a0 = fmaf(w[d2], y4.x, a0);
                a1 = fmaf(w[d2], y4.y, a1);
                a2 = fmaf(w[d2], y4.z, a2);
                a3 = fmaf(w[d2], y4.w, a3);
            }
            s_f[(t0 + 0) * 8 + j] = a0;
            s_f[(t0 + 1) * 8 + j] = a1;
            if (t0 + 2 < SEQ) s_f[(t0 + 2) * 8 + j] = a2;
            if (t0 + 3 < SEQ) s_f[(t0 + 3) * 8 + j] = a3;
        }
    }
    __syncthreads();

    // ---- Phase 6: logits[c] = out2000 . fc_w[c,:] + fc_b[c]  (float4 loads)
    {
        float* s_yf = (float*)s_dlu[p];
        float p_[NCLS];
        #pragma unroll
        for (int c = 0; c < NCLS; ++c) p_[c] = 0.f;
        const float4* fw4 = (const float4*)fc_w;
        const float4* sf4 = (const float4*)s_bc[p];
        for (int q = tid8; q < 500; q += 256) {
            float4 f = sf4[q];
            #pragma unroll
            for (int c = 0; c < NCLS; ++c) {
                float4 wv = fw4[c * 500 + q];
                p_[c] += f.x * wv.x + f.y * wv.y + f.z * wv.z + f.w * wv.w;
            }
        }
        #pragma unroll
        for (int c = 0; c < NCLS; ++c) {
            float v = p_[c];
            v = dpp_add<0xB1>(v);
            v = dpp_add<0x4E>(v);
            v = dpp_add<0x141>(v);
            v = dpp_add<0x140>(v);
            v += __shfl_xor(v, 16);
            v += __shfl_xor(v, 32);
            p_[c] = v;
        }
        const int wave = tid8 >> 6;
        const int lane = tid8 & 63;
        __syncthreads();
        if (lane == 0) {
            #pragma unroll
            for (int c = 0; c < NCLS; ++c) s_yf[wave * NCLS + c] = p_[c];
        }
        __syncthreads();
        if (tid8 < NCLS) {
            float v = s_yf[tid8] + s_yf[NCLS + tid8] + s_yf[2 * NCLS + tid8] +
                      s_yf[3 * NCLS + tid8] + fc_b[tid8];
            out[(size_t)(b0 + p) * NCLS + tid8] = v;
        }
    }
}

extern "C" void kernel_launch(void* const* d_in, const int* in_sizes, int n_in,
                              void* d_out, int out_size, void* d_ws, size_t ws_size,
                              hipStream_t stream) {
    const float* x          = (const float*)d_in[0];
    const float* in_proj_w  = (const float*)d_in[1];
    const float* conv_w     = (const float*)d_in[2];
    const float* conv_b     = (const float*)d_in[3];
    const float* x_proj_w   = (const float*)d_in[4];
    const float* dt_proj_w  = (const float*)d_in[5];
    const float* dt_proj_b  = (const float*)d_in[6];
    const float* A_log      = (const float*)d_in[7];
    const float* Dp         = (const float*)d_in[8];
    const float* out_proj_w = (const float*)d_in[9];
    const float* fc_w       = (const float*)d_in[10];
    const float* fc_b       = (const float*)d_in[11];
    float* out = (float*)d_out;

    const int batch = in_sizes[0] / (8 * SEQ);  // 1024
    mamba_cls_kernel<<<batch / 2, 512, 0, stream>>>(
        x, in_proj_w, conv_w, conv_b, x_proj_w, dt_proj_w, dt_proj_b,
        A_log, Dp, out_proj_w, fc_w, fc_b, out);
}

// Round 19
// 53.466 us; speedup vs baseline: 1.3260x; 1.2791x over previous
//
#include <hip/hip_runtime.h>
#include <hip/hip_fp16.h>
#include <math.h>

#define SEQ 250
#define ST  252      // padded t-stride: rows 16B-aligned (ST*4 = 1008 = 63*16)
#define NCLS 12

typedef __attribute__((ext_vector_type(4))) _Float16 half4v;
typedef __attribute__((ext_vector_type(4))) float    float4v;

// Butterfly add via DPP (zero DS-pipe ops).
// 0xB1=quad_perm xor1; 0x4E=quad_perm xor2; 0x141=row_half_mirror (lane^7,
// valid once quad-constant); 0x140=row_mirror (lane^15, once 8-group-constant).
template<int CTRL>
__device__ __forceinline__ float dpp_add(float v) {
    int t = __builtin_amdgcn_update_dpp(0, __float_as_int(v), CTRL, 0xF, 0xF, true);
    return v + __int_as_float(t);
}

__device__ __forceinline__ __half2 f_as_h2(float f) {
    union { float f; __half2 h; } u; u.f = f; return u.h;
}
__device__ __forceinline__ float h2_as_f(__half2 h) {
    union { __half2 h; float f; } u; u.h = h; return u.f;
}

// 512 threads, TWO batch elements per block. EXACT r14 restore (53.4 us).
// LDS: 2 x (s_bc 16128 + s_dlu 16128 + s_sz 8064) = 80,640 B -> 2 blocks/CU.
// r4-r6: no register live ranges across the scan (spills -> 45 MB scratch).
// r11/r12: matrix pipe takes the x_proj projection (ph3).
// r13: ph1-MFMA regressed (gather+cvt overhead) -> ph1/ph2 stay scalar.
// r15-r18: fold-4, ping-pong, parallel-split, ph1+2-fusion ALL regressed
// (issue vs VGPR/occupancy vs latency triangle) -> r14 is the measured
// optimum of this structure.
__global__ __launch_bounds__(512)
void mamba_cls_kernel(
    const float* __restrict__ x,         // (B, 8, 250)
    const float* __restrict__ in_proj_w, // (32, 8)
    const float* __restrict__ conv_w,    // (16, 4)
    const float* __restrict__ conv_b,    // (16)
    const float* __restrict__ x_proj_w,  // (33, 16)
    const float* __restrict__ dt_proj_w, // (16, 1)
    const float* __restrict__ dt_proj_b, // (16)
    const float* __restrict__ A_log,     // (16, 16)
    const float* __restrict__ Dp,        // (16)
    const float* __restrict__ out_proj_w,// (8, 16)
    const float* __restrict__ fc_w,      // (12, 2000)
    const float* __restrict__ fc_b,      // (12)
    float* __restrict__ out)             // (B, 12)
{
    __shared__ __align__(16) __half2 s_bc [2][16 * ST];
    __shared__ __align__(16) __half2 s_dlu[2][16 * ST];
    __shared__ __align__(16) __half  s_sz [2][16 * ST];

    const int tid  = threadIdx.x;
    const int p    = tid >> 8;
    const int tid8 = tid & 255;
    const int b0   = blockIdx.x * 2;

    // ---- Phase 0: stage x for BOTH problems coalesced (float4)
    {
        float4* s_xf4 = (float4*)s_dlu[0];
        const float4* __restrict__ xb4 =
            (const float4*)(x + (size_t)b0 * (8 * SEQ));
        for (int i = tid; i < 1000; i += 512) s_xf4[i] = xb4[i];
    }
    __syncthreads();

    // ---- Phase 1: x_in[d*ST+t] -> s_bc(f32) ; silu(z) -> s_sz   (r12 form)
    {
        float* s_f  = (float*)s_bc[p];
        const float* s_xf = (const float*)s_dlu[0] + p * (8 * SEQ);
        const int d  = tid8 & 15;
        const int t0 = tid8 >> 4;
        float w1[8], w2[8];
        #pragma unroll
        for (int m = 0; m < 8; ++m) {
            w1[m] = in_proj_w[d * 8 + m];
            w2[m] = in_proj_w[(16 + d) * 8 + m];
        }
        #pragma unroll
        for (int i = 0; i < 16; ++i) {
            int t = t0 + i * 16;
            if (t < SEQ) {
                float acc = 0.f, z = 0.f;
                #pragma unroll
                for (int m = 0; m < 8; ++m) {
                    float xv = s_xf[m * SEQ + t];
                    acc = fmaf(w1[m], xv, acc);
                    z   = fmaf(w2[m], xv, z);
                }
                s_f[d * ST + t] = acc;
                s_sz[p][d * ST + t] = __float2half(z / (1.f + __expf(-z)));
            }
        }
    }
    __syncthreads();

    // ---- Phase 2: causal conv(k=4)+SiLU -> u into s_dlu[p][d*ST+t].y (r12)
    {
        const float* s_f = (const float*)s_bc[p];
        const int d  = tid8 & 15;
        const int t0 = tid8 >> 4;
        float cw[4];
        #pragma unroll
        for (int k = 0; k < 4; ++k) cw[k] = conv_w[d * 4 + k];
        const float cb = conv_b[d];
        #pragma unroll
        for (int i = 0; i < 16; ++i) {
            int t = t0 + i * 16;
            if (t < SEQ) {
                float acc = cb;
                #pragma unroll
                for (int k = 0; k < 4; ++k) {
                    int tt = t + k - 3;
                    if (tt >= 0) acc = fmaf(cw[k], s_f[d * ST + tt], acc);
                }
                float sg = 1.f / (1.f + __expf(-acc));
                s_dlu[p][d * ST + t].y = __float2half(acc * sg);
            }
        }
    }
    __syncthreads();

    // ---- Phase 3 (MFMA): per 16-t tile, D = u(16t x 16d) * W(16d x 16col)
    // via v_mfma_f32_16x16x16f16 (fragment map verified r12).
    {
        const int wave = tid8 >> 6;       // 0..3
        const int l    = tid8 & 63;
        const int rowc = l & 15;          // A-row (t_local) AND D-col (state)
        const int kg   = l >> 4;          // k-group

        half4v wB, wC, wD;
        #pragma unroll
        for (int i = 0; i < 4; ++i) {
            wB[i] = (_Float16)x_proj_w[(1  + rowc) * 16 + 4 * kg + i];
            wC[i] = (_Float16)x_proj_w[(17 + rowc) * 16 + 4 * kg + i];
            wD[i] = (_Float16)x_proj_w[4 * kg + i];
        }
        const float dtw_c = dt_proj_w[rowc];
        const float dtb_c = dt_proj_b[rowc];
        const float4v zero4 = {0.f, 0.f, 0.f, 0.f};
        const unsigned int* __restrict__ dlu_w = (const unsigned int*)s_dlu[p];

        for (int tile = wave; tile < 16; tile += 4) {
            const int t0 = tile * 16;
            // A-frag: u[t0+rowc][4kg+i] = high half of {dl,u} word
            unsigned int w0 = dlu_w[(4 * kg + 0) * ST + t0 + rowc];
            unsigned int w1 = dlu_w[(4 * kg + 1) * ST + t0 + rowc];
            unsigned int w2 = dlu_w[(4 * kg + 2) * ST + t0 + rowc];
            unsigned int w3 = dlu_w[(4 * kg + 3) * ST + t0 + rowc];
            union { unsigned int u[2]; half4v h; } A;
            A.u[0] = (w0 >> 16) | (w1 & 0xFFFF0000u);
            A.u[1] = (w2 >> 16) | (w3 & 0xFFFF0000u);

            float4v dB = __builtin_amdgcn_mfma_f32_16x16x16f16(A.h, wB, zero4, 0, 0, 0);
            float4v dC = __builtin_amdgcn_mfma_f32_16x16x16f16(A.h, wC, zero4, 0, 0, 0);
            float4v dT = __builtin_amdgcn_mfma_f32_16x16x16f16(A.h, wD, zero4, 0, 0, 0);

            const int tb = t0 + kg * 4;   // first of this lane's 4 t's
            if (tb <= 248) {              // words tb..tb+3 <= 251 (pad ok)
                __half2 h0 = __floats2half2_rn(dB[0], dC[0]);
                __half2 h1 = __floats2half2_rn(dB[1], dC[1]);
                __half2 h2 = __floats2half2_rn(dB[2], dC[2]);
                __half2 h3 = __floats2half2_rn(dB[3], dC[3]);
                float4 wv;
                wv.x = h2_as_f(h0); wv.y = h2_as_f(h1);
                wv.z = h2_as_f(h2); wv.w = h2_as_f(h3);
                *reinterpret_cast<float4*>(s_bc[p] + rowc * ST + tb) = wv;
            }
            #pragma unroll
            for (int r = 0; r < 4; ++r) {
                int t = tb + r;
                if (t < SEQ) {
                    float v  = fmaf(dT[r], dtw_c, dtb_c);
                    float dl = (v > 20.f) ? v : __logf(1.f + __expf(v));
                    s_dlu[p][rowc * ST + t].x = __float2half(dl);
                }
            }
        }
    }
    __syncthreads();

    // ---- Phase 4: scan, s-folded x2, 8t batches: all 8 DS loads issue up
    // front (one lgkm region per 8t); y accumulated into float4 and written
    // as ONE masked b128 store per 4t. Active: tid<256 (waves 0-3).
    if (tid < 256) {
        const int sp   = tid >> 7;
        const int i7   = tid & 127;
        const int d    = i7 >> 3;
        const int s2   = i7 & 7;
        const float A2a = -__expf(A_log[d * 16 + s2])     * 1.4426950408889634f;
        const float A2b = -__expf(A_log[d * 16 + s2 + 8]) * 1.4426950408889634f;
        const float Dd  = Dp[d];
        const __half2* __restrict__ dlu_p = s_dlu[sp] + d * ST;
        const __half2* __restrict__ bca_p = s_bc [sp] + s2 * ST;
        const __half2* __restrict__ bcb_p = s_bc [sp] + (s2 + 8) * ST;
        const __half*  __restrict__ sz_p  = (const __half*)s_sz[sp] + d * ST;
        float* __restrict__ y_p = (float*)s_dlu[sp] + d * ST;
        float ha = 0.f, hb = 0.f;
        for (int t = 0; t < 248; t += 8) {
            // batched loads for 8 timesteps
            float4 du_a = *reinterpret_cast<const float4*>(dlu_p + t);
            float4 du_b = *reinterpret_cast<const float4*>(dlu_p + t + 4);
            float4 ba_a = *reinterpret_cast<const float4*>(bca_p + t);
            float4 ba_b = *reinterpret_cast<const float4*>(bca_p + t + 4);
            float4 bb_a = *reinterpret_cast<const float4*>(bcb_p + t);
            float4 bb_b = *reinterpret_cast<const float4*>(bcb_p + t + 4);
            float2 sza  = *reinterpret_cast<const float2*>(sz_p + t);
            float2 szb  = *reinterpret_cast<const float2*>(sz_p + t + 4);

            float fdu[8] = {du_a.x, du_a.y, du_a.z, du_a.w,
                            du_b.x, du_b.y, du_b.z, du_b.w};
            float fba[8] = {ba_a.x, ba_a.y, ba_a.z, ba_a.w,
                            ba_b.x, ba_b.y, ba_b.z, ba_b.w};
            float fbb[8] = {bb_a.x, bb_a.y, bb_a.z, bb_a.w,
                            bb_b.x, bb_b.y, bb_b.z, bb_b.w};
            float2 s0 = __half22float2(f_as_h2(sza.x));
            float2 s1 = __half22float2(f_as_h2(sza.y));
            float2 s2f = __half22float2(f_as_h2(szb.x));
            float2 s3 = __half22float2(f_as_h2(szb.y));
            float fsz[8] = {s0.x, s0.y, s1.x, s1.y, s2f.x, s2f.y, s3.x, s3.y};

            float yv[8];
            #pragma unroll
            for (int tt = 0; tt < 8; ++tt) {
                float2 du  = __half22float2(f_as_h2(fdu[tt]));
                float2 bca = __half22float2(f_as_h2(fba[tt]));
                float2 bcb = __half22float2(f_as_h2(fbb[tt]));
                float dlu = du.x * du.y;
                ha = fmaf(exp2f(du.x * A2a), ha, dlu * bca.x);
                hb = fmaf(exp2f(du.x * A2b), hb, dlu * bcb.x);
                float r = fmaf(hb, bcb.y, ha * bca.y);
                r = dpp_add<0xB1>(r);
                r = dpp_add<0x4E>(r);
                r = dpp_add<0x141>(r);
                yv[tt] = fmaf(du.y, Dd, r) * fsz[tt];
            }
            if (s2 == 0) {
                float4 y4;
                y4.x = yv[0]; y4.y = yv[1]; y4.z = yv[2]; y4.w = yv[3];
                *reinterpret_cast<float4*>(y_p + t) = y4;
                y4.x = yv[4]; y4.y = yv[5]; y4.z = yv[6]; y4.w = yv[7];
                *reinterpret_cast<float4*>(y_p + t + 4) = y4;
            }
        }
        {   // tail t = 248, 249
            float2 duv2 = *reinterpret_cast<const float2*>(dlu_p + 248);
            float2 bca2 = *reinterpret_cast<const float2*>(bca_p + 248);
            float2 bcb2 = *reinterpret_cast<const float2*>(bcb_p + 248);
            float2 szf  = __half22float2(*reinterpret_cast<const __half2*>(sz_p + 248));
            float fdu[2] = {duv2.x, duv2.y};
            float fba[2] = {bca2.x, bca2.y};
            float fbb[2] = {bcb2.x, bcb2.y};
            float fsz[2] = {szf.x, szf.y};
            float yv[2];
            #pragma unroll
            for (int tt = 0; tt < 2; ++tt) {
                float2 du  = __half22float2(f_as_h2(fdu[tt]));
                float2 bca = __half22float2(f_as_h2(fba[tt]));
                float2 bcb = __half22float2(f_as_h2(fbb[tt]));
                float dlu = du.x * du.y;
                ha = fmaf(exp2f(du.x * A2a), ha, dlu * bca.x);
                hb = fmaf(exp2f(du.x * A2b), hb, dlu * bcb.x);
                float r = fmaf(hb, bcb.y, ha * bca.y);
                r = dpp_add<0xB1>(r);
                r = dpp_add<0x4E>(r);
                r = dpp_add<0x141>(r);
                yv[tt] = fmaf(du.y, Dd, r) * fsz[tt];
            }
            if (s2 == 0) {
                float2 y2; y2.x = yv[0]; y2.y = yv[1];
                *reinterpret_cast<float2*>(y_p + 248) = y2;
            }
        }
    }
    __syncthreads();

    // ---- Phase 5b: out2000[t*8+j] = sum_d y[d,t]*out_proj_w[j,d]
    // Mapping: j = tid8&7, 4t-chunk = tid8>>3; y read as b128 per d-row.
    {
        float* s_f  = (float*)s_bc[p];
        const float* s_yf = (const float*)s_dlu[p];
        const int j = tid8 & 7;
        float w[16];
        #pragma unroll
        for (int d2 = 0; d2 < 16; ++d2) w[d2] = out_proj_w[j * 16 + d2];
        for (int t0 = (tid8 >> 3) * 4; t0 < SEQ; t0 += 128) {
            float a0 = 0.f, a1 = 0.f, a2 = 0.f, a3 = 0.f;
            #pragma unroll
            for (int d2 = 0; d2 < 16; ++d2) {
                float4 y4 = *reinterpret_cast<const float4*>(s_yf + d2 * ST + t0);
                a0 = fmaf(w[d2], y4.x, a0);
                a1 = fmaf(w[d2], y4.y, a1);
                a2 = fmaf(w[d2], y4.z, a2);
                a3 = fmaf(w[d2], y4.w, a3);
            }
            s_f[(t0 + 0) * 8 + j] = a0;
            s_f[(t0 + 1) * 8 + j] = a1;
            if (t0 + 2 < SEQ) s_f[(t0 + 2) * 8 + j] = a2;
            if (t0 + 3 < SEQ) s_f[(t0 + 3) * 8 + j] = a3;
        }
    }
    __syncthreads();

    // ---- Phase 6: logits[c] = out2000 . fc_w[c,:] + fc_b[c]  (float4 loads)
    {
        float* s_yf = (float*)s_dlu[p];
        float p_[NCLS];
        #pragma unroll
        for (int c = 0; c < NCLS; ++c) p_[c] = 0.f;
        const float4* fw4 = (const float4*)fc_w;
        const float4* sf4 = (const float4*)s_bc[p];
        for (int q = tid8; q < 500; q += 256) {
            float4 f = sf4[q];
            #pragma unroll
            for (int c = 0; c < NCLS; ++c) {
                float4 wv = fw4[c * 500 + q];
                p_[c] += f.x * wv.x + f.y * wv.y + f.z * wv.z + f.w * wv.w;
            }
        }
        #pragma unroll
        for (int c = 0; c < NCLS; ++c) {
            float v = p_[c];
            v = dpp_add<0xB1>(v);
            v = dpp_add<0x4E>(v);
            v = dpp_add<0x141>(v);
            v = dpp_add<0x140>(v);
            v += __shfl_xor(v, 16);
            v += __shfl_xor(v, 32);
            p_[c] = v;
        }
        const int wave = tid8 >> 6;
        const int lane = tid8 & 63;
        __syncthreads();
        if (lane == 0) {
            #pragma unroll
            for (int c = 0; c < NCLS; ++c) s_yf[wave * NCLS + c] = p_[c];
        }
        __syncthreads();
        if (tid8 < NCLS) {
            float v = s_yf[tid8] + s_yf[NCLS + tid8] + s_yf[2 * NCLS + tid8] +
                      s_yf[3 * NCLS + tid8] + fc_b[tid8];
            out[(size_t)(b0 + p) * NCLS + tid8] = v;
        }
    }
}

extern "C" void kernel_launch(void* const* d_in, const int* in_sizes, int n_in,
                              void* d_out, int out_size, void* d_ws, size_t ws_size,
                              hipStream_t stream) {
    const float* x          = (const float*)d_in[0];
    const float* in_proj_w  = (const float*)d_in[1];
    const float* conv_w     = (const float*)d_in[2];
    const float* conv_b     = (const float*)d_in[3];
    const float* x_proj_w   = (const float*)d_in[4];
    const float* dt_proj_w  = (const float*)d_in[5];
    const float* dt_proj_b  = (const float*)d_in[6];
    const float* A_log      = (const float*)d_in[7];
    const float* Dp         = (const float*)d_in[8];
    const float* out_proj_w = (const float*)d_in[9];
    const float* fc_w       = (const float*)d_in[10];
    const float* fc_b       = (const float*)d_in[11];
    float* out = (float*)d_out;

    const int batch = in_sizes[0] / (8 * SEQ);  // 1024
    mamba_cls_kernel<<<batch / 2, 512, 0, stream>>>(
        x, in_proj_w, conv_w, conv_b, x_proj_w, dt_proj_w, dt_proj_b,
        A_log, Dp, out_proj_w, fc_w, fc_b, out);
}